// Round 10
// baseline (64.437 us; speedup 1.0000x reference)
//
#include <hip/hip_runtime.h>
#include <math.h>

#define BATCH 2
#define NNODE 512
#define DIN   128
#define DOUT  128
#define DE    32
#define NEG   0.2f
#define TI    8       // i-rows per score block
#define TJ    64      // j-cols per score block (4 waves x 16)
#define TIB   4       // i-rows per agg block

typedef __attribute__((ext_vector_type(8))) short bf16x8;
typedef __attribute__((ext_vector_type(4))) float f32x4;

__device__ inline short f2bf(float f) {   // RNE f32 -> bf16
    union { float f; unsigned u; } v; v.f = f;
    unsigned r = v.u + 0x7fffu + ((v.u >> 16) & 1u);
    return (short)(r >> 16);
}

// VALU-only 16-lane sum via DPP row-rotate (no DS ops, no lgkm waits).
template<int CTRL>
__device__ inline float dpp_add(float x) {
    const int y = __builtin_amdgcn_update_dpp(0, __float_as_int(x), CTRL, 0xF, 0xF, false);
    return x + __int_as_float(y);
}
__device__ inline float row16_sum(float x) {
    x = dpp_add<0x128>(x);   // row_ror:8
    x = dpp_add<0x124>(x);   // row_ror:4
    x = dpp_add<0x122>(x);   // row_ror:2
    x = dpp_add<0x121>(x);   // row_ror:1
    return x;                // all 16 lanes hold the full sum
}

// ---------------------------------------------------------------------------
// Kernel 1: x_l = x@W_l + b_l ; x_r = x@W_r + b_r   (4 rows/block)
// ---------------------------------------------------------------------------
__global__ __launch_bounds__(256) void xlr_kernel(
    const float* __restrict__ x,  const float* __restrict__ Wl,
    const float* __restrict__ bl, const float* __restrict__ Wr,
    const float* __restrict__ br, float* __restrict__ xl,
    float* __restrict__ xr)
{
    const int r0 = blockIdx.x * 4;
    const int d  = threadIdx.x & 127;
    const int hv = threadIdx.x >> 7;
    __shared__ float xs[4][DIN];
    for (int idx = threadIdx.x; idx < 4 * DIN; idx += 256)
        xs[idx >> 7][idx & 127] = x[(size_t)r0 * DIN + idx];
    __syncthreads();
    const int ra = 2 * hv, rb = ra + 1;
    float al0 = bl[d], al1 = al0, ar0 = br[d], ar1 = ar0;
    #pragma unroll 4
    for (int k = 0; k < DIN; ++k) {
        const float wl = Wl[k * DOUT + d], wr = Wr[k * DOUT + d];
        const float xa = xs[ra][k], xb = xs[rb][k];
        al0 = fmaf(xa, wl, al0); al1 = fmaf(xb, wl, al1);
        ar0 = fmaf(xa, wr, ar0); ar1 = fmaf(xb, wr, ar1);
    }
    xl[(size_t)(r0 + ra) * DOUT + d] = al0;
    xl[(size_t)(r0 + rb) * DOUT + d] = al1;
    xr[(size_t)(r0 + ra) * DOUT + d] = ar0;
    xr[(size_t)(r0 + rb) * DOUT + d] = ar1;
}

// ---------------------------------------------------------------------------
// Kernel 2 (score): block = (b, 8-i tile, 64-j tile). xl lives in the MFMA
// C-input (free accumulator-init); score reduction is DPP row-rotate (VALU
// only, no DS latency chain). Depth-1 e-prefetch across the i-loop.
// ---------------------------------------------------------------------------
__global__ __launch_bounds__(256, 4) void score_kernel(
    const float* __restrict__ xl, const float* __restrict__ xr,
    const void* __restrict__ adjv, const float* __restrict__ e,
    const float* __restrict__ We, const float* __restrict__ att,
    float* __restrict__ sc)
{
    const int bid = blockIdx.x;          // 1024 blocks: (b, iT:64, jT:8)
    const int jT  = bid & 7;
    const int iT  = (bid >> 3) & 63;
    const int b   = bid >> 9;
    const int i0  = iT * TI, j0 = jT * TJ;
    const int t    = threadIdx.x;
    const int wave = t >> 6;
    const int lane = t & 63;
    const int col  = lane & 15;
    const int g    = lane >> 4;

    __shared__ short WeT_s[DOUT][DE];        // 8 KB  [d][k] bf16
    __shared__ float xr_s[TI][DOUT];         // 4 KB
    __shared__ float att_s[DOUT];
    __shared__ int   mflag[2];

    if (t < 2) mflag[t] = 0;
    for (int idx = t; idx < DE * DOUT; idx += 256) {
        const int k = idx >> 7, d = idx & 127;
        WeT_s[d][k] = f2bf(We[idx]);
    }
    for (int idx = t; idx < TI * DOUT; idx += 256) {
        const int ii = idx >> 7, d = idx & 127;
        xr_s[ii][d] = xr[(size_t)(b * NNODE + i0 + ii) * DOUT + d];
    }
    if (t < DOUT) att_s[t] = att[t];
    // adj dtype probe (first 16 KB, L2-resident)
    {
        const unsigned* aw = (const unsigned*)adjv;
        unsigned sawF = 0, sawG = 0;
        #pragma unroll
        for (int k = 0; k < 16; ++k) {
            const unsigned w = aw[t + 256 * k];
            sawF |= (w == 0x3f800000u);
            sawG |= (w > 1u);
        }
        if (sawF) atomicOr(&mflag[0], 1);
        if (sawG) atomicOr(&mflag[1], 1);
    }

    // xl -> MFMA C-init registers: lane needs xl[jw + g*4 + r][dt*16 + col],
    // invariant across the i-loop. 32 f32 regs as 8x f32x4.
    f32x4 xlv4[8];
    {
        const float* xb = xl + (size_t)(b * NNODE + j0 + wave * 16 + g * 4) * DOUT + col;
        #pragma unroll
        for (int dt = 0; dt < 8; ++dt)
            #pragma unroll
            for (int r = 0; r < 4; ++r)
                xlv4[dt][r] = xb[(size_t)r * DOUT + dt * 16];
    }
    __syncthreads();
    const int byteMode = (!mflag[0] && mflag[1]) ? 1 : 0;

    bf16x8 bf[8];
    float  atv[8];
    #pragma unroll
    for (int dt = 0; dt < 8; ++dt) {
        bf[dt]  = *(const bf16x8*)&WeT_s[dt * 16 + col][g * 8];
        atv[dt] = att_s[dt * 16 + col];
    }

    const int jw = j0 + wave * 16;           // this wave's 16-j tile
    const float* ebase = e + ((size_t)(b * NNODE + i0) * NNODE + jw + col) * DE + g * 8;
    const size_t estep = (size_t)NNODE * DE; // per-i stride

    f32x4 a0 = *(const f32x4*)ebase;
    f32x4 a1 = *(const f32x4*)(ebase + 4);

    for (int i = 0; i < TI; ++i) {
        f32x4 a0n, a1n;
        if (i + 1 < TI) {                    // depth-1 prefetch of next i
            const float* apn = ebase + (size_t)(i + 1) * estep;
            a0n = *(const f32x4*)apn;
            a1n = *(const f32x4*)(apn + 4);
        }
        bf16x8 af;
        af[0] = f2bf(a0[0]); af[1] = f2bf(a0[1]);
        af[2] = f2bf(a0[2]); af[3] = f2bf(a0[3]);
        af[4] = f2bf(a1[0]); af[5] = f2bf(a1[1]);
        af[6] = f2bf(a1[2]); af[7] = f2bf(a1[3]);

        float part[4] = {0.f, 0.f, 0.f, 0.f};
        #pragma unroll
        for (int dt = 0; dt < 8; ++dt) {     // MFMA with C-in = xl (free add)
            const f32x4 c = __builtin_amdgcn_mfma_f32_16x16x32_bf16(af, bf[dt], xlv4[dt], 0, 0, 0);
            const float xrv = xr_s[i][dt * 16 + col];
            #pragma unroll
            for (int r = 0; r < 4; ++r) {
                float p = c[r] + xrv;
                p = fmaxf(p, NEG * p);       // leaky_relu
                part[r] = fmaf(atv[dt], p, part[r]);
            }
        }
        #pragma unroll
        for (int r = 0; r < 4; ++r)
            part[r] = row16_sum(part[r]);    // VALU-only 16-lane reduce

        if (col == 0) {
            const int ig = i0 + i;
            const int jb = jw + g * 4;
            const unsigned char* aB = (const unsigned char*)adjv + (size_t)(b * NNODE + ig) * NNODE;
            const unsigned*      aW = (const unsigned*)adjv + (size_t)(b * NNODE + ig) * NNODE;
            float4 v;
            float* vp = (float*)&v;
            #pragma unroll
            for (int r = 0; r < 4; ++r) {
                const int j = jb + r;
                const bool conn = (j == ig) ||
                    (byteMode ? (aB[j] != 0) : (aW[j] != 0));
                vp[r] = conn ? part[r] : -1e30f;
            }
            *(float4*)&sc[(size_t)(b * NNODE + ig) * NNODE + jb] = v;
        }
        a0 = a0n; a1 = a1n;
    }
}

// ---------------------------------------------------------------------------
// Kernel 3 (agg): block = (b, 4-i tile, d-half). 512 blocks (2/CU). One row
// per wave: wave-local softmax, then alpha @ x_l with 4-way j-unroll
// (4 independent load+FMA chains).
// ---------------------------------------------------------------------------
__global__ __launch_bounds__(256) void agg_kernel(
    const float* __restrict__ xl, const float* __restrict__ sc,
    const void* __restrict__ adjv, const void* __restrict__ maskv,
    const float* __restrict__ bias, float* __restrict__ out)
{
    const int bid = blockIdx.x;          // 512 blocks: (b, iT:128, dh:2)
    const int dh  = bid & 1;
    const int iT  = (bid >> 1) & 127;
    const int b   = bid >> 8;
    const int i0  = iT * TIB, d0 = dh * 64;
    const int t    = threadIdx.x;
    const int wave = t >> 6;
    const int lane = t & 63;

    __shared__ float al_s[TIB][NNODE];   // 8 KB
    __shared__ int   mflag[2];

    if (t < 2) mflag[t] = 0;
    {
        const unsigned* aw = (const unsigned*)adjv;
        unsigned sawF = 0, sawG = 0;
        #pragma unroll
        for (int k = 0; k < 16; ++k) {
            const unsigned w = aw[t + 256 * k];
            sawF |= (w == 0x3f800000u);
            sawG |= (w > 1u);
        }
        if (sawF) atomicOr(&mflag[0], 1);
        if (sawG) atomicOr(&mflag[1], 1);
    }
    for (int idx = t; idx < TIB * NNODE; idx += 256) {
        const int r = idx >> 9, jj = idx & 511;
        al_s[r][jj] = sc[(size_t)(b * NNODE + i0 + r) * NNODE + jj];
    }
    __syncthreads();
    const int byteMode = (!mflag[0] && mflag[1]) ? 1 : 0;

    // wave-local softmax on row `wave` (each wave consumes only its own row)
    float inv;
    {
        float v[8], m = -1e30f;
        #pragma unroll
        for (int k = 0; k < 8; ++k) {
            v[k] = al_s[wave][lane + 64 * k];
            m = fmaxf(m, v[k]);
        }
        #pragma unroll
        for (int off = 32; off; off >>= 1) m = fmaxf(m, __shfl_xor(m, off, 64));
        float s = 0.f;
        #pragma unroll
        for (int k = 0; k < 8; ++k) {
            const float ex = __expf(v[k] - m);
            al_s[wave][lane + 64 * k] = ex;
            s += ex;
        }
        #pragma unroll
        for (int off = 32; off; off >>= 1) s += __shfl_xor(s, off, 64);
        inv = 1.f / s;
    }

    // aggregation: row i0+wave, cols d0+lane; 4 independent chains
    const int d = d0 + lane;
    const float* xb = xl + (size_t)b * NNODE * DOUT + d;
    float ac0 = 0.f, ac1 = 0.f, ac2 = 0.f, ac3 = 0.f;
    #pragma unroll 2
    for (int j = 0; j < NNODE; j += 4) {
        ac0 = fmaf(al_s[wave][j],     xb[(size_t)j * DOUT],       ac0);
        ac1 = fmaf(al_s[wave][j + 1], xb[(size_t)(j + 1) * DOUT], ac1);
        ac2 = fmaf(al_s[wave][j + 2], xb[(size_t)(j + 2) * DOUT], ac2);
        ac3 = fmaf(al_s[wave][j + 3], xb[(size_t)(j + 3) * DOUT], ac3);
    }
    const int mi = b * NNODE + i0 + wave;
    const bool mv = byteMode ? (((const unsigned char*)maskv)[mi] != 0)
                             : (((const unsigned*)maskv)[mi] != 0);
    float val = ((ac0 + ac1) + (ac2 + ac3)) * inv + bias[d];
    if (!mv) val = 0.f;
    val = val / (1.f + __expf(-val));    // silu
    out[(size_t)mi * DOUT + d] = val;
}

// ---------------------------------------------------------------------------
extern "C" void kernel_launch(void* const* d_in, const int* in_sizes, int n_in,
                              void* d_out, int out_size, void* d_ws, size_t ws_size,
                              hipStream_t stream)
{
    const float* x    = (const float*)d_in[0];
    const void*  adj  = d_in[1];
    const float* e    = (const float*)d_in[2];
    const void*  mask = d_in[3];
    const float* Wl   = (const float*)d_in[4];
    const float* bl   = (const float*)d_in[5];
    const float* Wr   = (const float*)d_in[6];
    const float* br   = (const float*)d_in[7];
    const float* We   = (const float*)d_in[8];
    const float* att  = (const float*)d_in[9];
    const float* bias = (const float*)d_in[10];
    float*       out  = (float*)d_out;

    float* xl = (float*)d_ws;                              // 512 KB
    float* xr = xl + (size_t)BATCH * NNODE * DOUT;         // 512 KB
    float* sc = xr + (size_t)BATCH * NNODE * DOUT;         // 2 MB scores

    xlr_kernel<<<(BATCH * NNODE) / 4, 256, 0, stream>>>(x, Wl, bl, Wr, br, xl, xr);
    score_kernel<<<BATCH * (NNODE / TI) * (NNODE / TJ), 256, 0, stream>>>(
        xl, xr, adj, e, We, att, sc);
    agg_kernel<<<BATCH * (NNODE / TIB) * 2, 256, 0, stream>>>(
        xl, sc, adj, mask, bias, out);
}